// Round 8
// baseline (930.076 us; speedup 1.0000x reference)
//
#include <hip/hip_runtime.h>
#include <hip/hip_bf16.h>

// Problem constants (match reference)
#define KS_FULL 5
#define INC 64
#define OUTC 64
#define RUN_INC 48
#define RUN_OUTC 48
#define NPTS 200000
#define MPAIR 150000
#define K_RUN 27
#define NPAIRS (K_RUN * MPAIR)                 // 4,050,000

// Row-chunk / bucket sort geometry
#define CHUNK_ROWS 128
#define NCHUNK ((NPTS + CHUNK_ROWS - 1) / CHUNK_ROWS)   // 1563
#define NBUCK (NCHUNK * K_RUN)                          // 42,201
#define NSCANB (NBUCK + 1)                              // 42,202
#define SCAN_CHUNK 1024
#define NB1 ((NSCANB + SCAN_CHUNK - 1) / SCAN_CHUNK)    // 42

// d_ws layout (byte offsets). Need ~37.2 MB (R5 confirmed ws >= 39.5 MB).
#define OFF_COUNTS  0u                         // int[NSCANB] = 169 KB
#define OFF_OFFSETS (256u << 10)               // int[NSCANB]
#define OFF_CURSOR  (512u << 10)               // int[NBUCK]
#define OFF_BSUMS   (768u << 10)               // int[NB1]
#define OFF_WBF     (832u << 10)               // ushort[27*6*48*8] = 124,416 B
#define OFF_FBF     (1u << 20)                 // ushort[200000*48] = 19.2 MB
#define OFF_SORTED  (21u << 20)                // int[NPAIRS] = 16.2 MB
#define WS_NEED ((size_t)OFF_SORTED + (size_t)NPAIRS * 4)

// ---------------------------------------------------------------------------
// bf16 helpers
__device__ __forceinline__ unsigned short bf_rne(float x) {
    unsigned u = __float_as_uint(x);
    u += 0x7FFFu + ((u >> 16) & 1u);
    return (unsigned short)(u >> 16);
}
__device__ __forceinline__ unsigned pack2bf(float lo, float hi) {
    return (unsigned)bf_rne(lo) | ((unsigned)bf_rne(hi) << 16);
}

#if defined(__has_builtin)
#if __has_builtin(__builtin_amdgcn_fdot2_f32_bf16)
#define HAVE_DOT2 1
#endif
#endif

#ifdef HAVE_DOT2
typedef __bf16 bf16x2 __attribute__((ext_vector_type(2)));
__device__ __forceinline__ float dot2bf(unsigned w, unsigned f, float c) {
    return __builtin_amdgcn_fdot2_f32_bf16(__builtin_bit_cast(bf16x2, w),
                                           __builtin_bit_cast(bf16x2, f), c, false);
}
#else
__device__ __forceinline__ float dot2bf(unsigned w, unsigned f, float c) {
    c = fmaf(__uint_as_float(w << 16), __uint_as_float(f << 16), c);
    c = fmaf(__uint_as_float(w & 0xFFFF0000u), __uint_as_float(f & 0xFFFF0000u), c);
    return c;
}
#endif

// ---------------------------------------------------------------------------
// prep: 27x48x48 center sub-kernel -> bf16, layout [k][ic=i/8][o][i%8]
__global__ __launch_bounds__(256) void prep_wbf(
    const float* __restrict__ kernel, unsigned short* __restrict__ wbf)
{
    int t = blockIdx.x * 256 + threadIdx.x;
    if (t >= K_RUN * RUN_INC * RUN_OUTC) return;
    int k = t / (RUN_INC * RUN_OUTC);
    int r = t - k * (RUN_INC * RUN_OUTC);
    int i = r / RUN_OUTC;
    int o = r - i * RUN_OUTC;
    int a = k / 9, b = (k / 3) % 3, c = k % 3;
    int kf = (a + 1) * (KS_FULL * KS_FULL) + (b + 1) * KS_FULL + (c + 1);
    float v = kernel[(size_t)kf * (INC * OUTC) + i * OUTC + o];
    wbf[(((k * 6 + (i >> 3)) * RUN_OUTC + o) << 3) + (i & 7)] = bf_rne(v);
}

// prep: features fp32 -> packed bf16 (8 floats / thread)
__global__ __launch_bounds__(256) void prep_fbf(
    const float4* __restrict__ f4, uint4* __restrict__ fb4)
{
    int t = blockIdx.x * 256 + threadIdx.x;
    if (t >= (NPTS * RUN_INC) / 8) return;
    float4 a = f4[2 * t], b = f4[2 * t + 1];
    uint4 o;
    o.x = pack2bf(a.x, a.y); o.y = pack2bf(a.z, a.w);
    o.z = pack2bf(b.x, b.y); o.w = pack2bf(b.z, b.w);
    fb4[t] = o;
}

// ---------------------------------------------------------------------------
// hist: bucket = (out_row/128)*27 + k
__global__ __launch_bounds__(256) void hist_kernel(
    const int4* __restrict__ out_idx4, const int4* __restrict__ mask4,
    int* __restrict__ counts)
{
    int t = blockIdx.x * 256 + threadIdx.x;
    if (t >= MPAIR / 4) return;
    int k = blockIdx.y;
    int base = k * (MPAIR / 4) + t;
    int4 mk = mask4[base];
    int4 oi = out_idx4[base];
    if (mk.x) atomicAdd(&counts[(oi.x >> 7) * K_RUN + k], 1);
    if (mk.y) atomicAdd(&counts[(oi.y >> 7) * K_RUN + k], 1);
    if (mk.z) atomicAdd(&counts[(oi.z >> 7) * K_RUN + k], 1);
    if (mk.w) atomicAdd(&counts[(oi.w >> 7) * K_RUN + k], 1);
}

// ---------------------------------------------------------------------------
// scan1/2/3: exclusive scan of counts[NSCANB] -> offsets (+ cursor copy)
__global__ __launch_bounds__(256) void scan1_kernel(
    const int* __restrict__ counts, int* __restrict__ offsets,
    int* __restrict__ bsums)
{
    __shared__ int sh[2][256];
    int b = blockIdx.x, t = threadIdx.x;
    int gbase = b * SCAN_CHUNK + t * 4;
    int v0 = (gbase + 0 < NSCANB) ? counts[gbase + 0] : 0;
    int v1 = (gbase + 1 < NSCANB) ? counts[gbase + 1] : 0;
    int v2 = (gbase + 2 < NSCANB) ? counts[gbase + 2] : 0;
    int v3 = (gbase + 3 < NSCANB) ? counts[gbase + 3] : 0;
    int tsum = v0 + v1 + v2 + v3;
    sh[0][t] = tsum;
    __syncthreads();
    int src = 0;
    for (int d = 1; d < 256; d <<= 1) {
        int dst = src ^ 1;
        sh[dst][t] = sh[src][t] + ((t >= d) ? sh[src][t - d] : 0);
        __syncthreads();
        src = dst;
    }
    int incl = sh[src][t];
    int excl = incl - tsum;
    if (t == 255) bsums[b] = incl;
    int run = excl;
    if (gbase + 0 < NSCANB) { offsets[gbase + 0] = run; } run += v0;
    if (gbase + 1 < NSCANB) { offsets[gbase + 1] = run; } run += v1;
    if (gbase + 2 < NSCANB) { offsets[gbase + 2] = run; } run += v2;
    if (gbase + 3 < NSCANB) { offsets[gbase + 3] = run; }
}

__global__ __launch_bounds__(256) void scan2_kernel(int* __restrict__ bsums)
{
    __shared__ int sh[2][256];
    int t = threadIdx.x;
    int v = (t < NB1) ? bsums[t] : 0;
    sh[0][t] = v;
    __syncthreads();
    int src = 0;
    for (int d = 1; d < 256; d <<= 1) {
        int dst = src ^ 1;
        sh[dst][t] = sh[src][t] + ((t >= d) ? sh[src][t - d] : 0);
        __syncthreads();
        src = dst;
    }
    if (t < NB1) bsums[t] = sh[src][t] - v;  // exclusive
}

__global__ __launch_bounds__(256) void scan3_kernel(
    int* __restrict__ offsets, const int* __restrict__ bsums,
    int* __restrict__ cursor)
{
    int gi = blockIdx.x * 256 + threadIdx.x;
    if (gi < NSCANB) {
        int v = offsets[gi] + bsums[gi >> 10];
        offsets[gi] = v;
        if (gi < NBUCK) cursor[gi] = v;
    }
}

// ---------------------------------------------------------------------------
// fill: scatter packed (in_row | row_lo<<18 | k<<25) into bucket-sorted slots
__global__ __launch_bounds__(256) void fill_kernel(
    const int4* __restrict__ in_idx4, const int4* __restrict__ out_idx4,
    const int4* __restrict__ mask4, int* __restrict__ cursor,
    int* __restrict__ sorted)
{
    int t = blockIdx.x * 256 + threadIdx.x;
    if (t >= MPAIR / 4) return;
    int k = blockIdx.y;
    int base = k * (MPAIR / 4) + t;
    int4 mk = mask4[base];
    int4 oi = out_idx4[base];
    int4 ii = in_idx4[base];
    int kk = k << 25;
    if (mk.x) { int pos = atomicAdd(&cursor[(oi.x >> 7) * K_RUN + k], 1);
                sorted[pos] = ii.x | ((oi.x & 127) << 18) | kk; }
    if (mk.y) { int pos = atomicAdd(&cursor[(oi.y >> 7) * K_RUN + k], 1);
                sorted[pos] = ii.y | ((oi.y & 127) << 18) | kk; }
    if (mk.z) { int pos = atomicAdd(&cursor[(oi.z >> 7) * K_RUN + k], 1);
                sorted[pos] = ii.z | ((oi.z & 127) << 18) | kk; }
    if (mk.w) { int pos = atomicAdd(&cursor[(oi.w >> 7) * K_RUN + k], 1);
                sorted[pos] = ii.w | ((oi.w & 127) << 18) | kk; }
}

// ---------------------------------------------------------------------------
// accum v4: one block per 128-row chunk. Pairs within chunk are k-sorted, so
// W[k] is held in REGISTERS (6 uint4/lane, reloaded ~4x per wave). Per-pair
// sums go to an LDS acc tile [128][48] via LDS atomics; block writes the tile
// out coalesced (covers every row -> no out memset). f-gather double-buffered.
// NOTE: macro params must NOT be named w/f/x/y/z — member-access tokens like
// `w.w` get double-substituted (R7 compile failure).
#define LOADF(Fr, e) do { const uint4* fp_ = fbf4 + (size_t)((e) & 0x3FFFF) * 6; \
    Fr##0 = fp_[0]; Fr##1 = fp_[1]; Fr##2 = fp_[2];                              \
    Fr##3 = fp_[3]; Fr##4 = fp_[4]; Fr##5 = fp_[5]; } while (0)

#define LOADW(kk) do { const uint4* wp_ = wbf4 + (size_t)(kk) * (6 * RUN_OUTC) + wo; \
    w0 = wp_[0]; w1 = wp_[RUN_OUTC]; w2 = wp_[2 * RUN_OUTC];                         \
    w3 = wp_[3 * RUN_OUTC]; w4 = wp_[4 * RUN_OUTC]; w5 = wp_[5 * RUN_OUTC]; } while (0)

#define DOTIC(Wv, Fv)                                         \
    a0 = dot2bf(Wv.x, Fv.x, a0); a1 = dot2bf(Wv.y, Fv.y, a1); \
    a2 = dot2bf(Wv.z, Fv.z, a2); a3 = dot2bf(Wv.w, Fv.w, a3);

#define COMPUTE(Fr, e) do {                                   \
    float a0 = 0.f, a1 = 0.f, a2 = 0.f, a3 = 0.f;             \
    DOTIC(w0, Fr##0) DOTIC(w1, Fr##1) DOTIC(w2, Fr##2)        \
    DOTIC(w3, Fr##3) DOTIC(w4, Fr##4) DOTIC(w5, Fr##5)        \
    float s_ = (a0 + a1) + (a2 + a3);                         \
    int rl_ = ((e) >> 18) & (CHUNK_ROWS - 1);                 \
    if (lane < RUN_OUTC)                                      \
        atomicAdd(&accS[rl_ * RUN_OUTC + lane], s_);          \
} while (0)

__global__ __launch_bounds__(512, 4) void accum5_kernel(
    const uint4* __restrict__ fbf4,     // bf16 features, 6 uint4 per row
    const uint4* __restrict__ wbf4,     // 27*6*48 uint4, k-major
    const int* __restrict__ offsets,    // bucket offsets (NSCANB)
    const int* __restrict__ sorted,
    float4* __restrict__ out4)
{
    __shared__ float accS[CHUNK_ROWS * RUN_OUTC];   // 24,576 B
    const int chunk = blockIdx.x;
    for (int i = threadIdx.x; i < CHUNK_ROWS * RUN_OUTC; i += 512) accS[i] = 0.f;
    __syncthreads();

    const int lane = threadIdx.x & 63;
    const int wv   = threadIdx.x >> 6;                       // 0..7
    const int wo   = (lane < RUN_OUTC) ? lane : lane - RUN_OUTC;
    const int S = offsets[chunk * K_RUN];
    const int E = offsets[(chunk + 1) * K_RUN];
    const int P = E - S;
    int p        = S + (int)(((long long)P * wv) >> 3);
    const int p1 = S + (int)(((long long)P * (wv + 1)) >> 3);

    if (p < p1) {
        uint4 w0, w1, w2, w3, w4, w5;
        uint4 fa0, fa1, fa2, fa3, fa4, fa5;
        uint4 fb0, fb1, fb2, fb3, fb4, fb5;
        int ec = sorted[p];
        LOADF(fa, ec);
        int curk = -1;
        for (;;) {
            // A: prefetch pair p+1 into fb, compute pair p (fa)
            int pn = (p + 1 < p1) ? p + 1 : p;
            int en = sorted[pn];
            LOADF(fb, en);
            int kk = ec >> 25;                    // wave-uniform
            if (kk != curk) { curk = kk; LOADW(kk); }
            COMPUTE(fa, ec);
            if (++p >= p1) break;
            // B: prefetch pair p+1 into fa, compute pair p (fb)
            int pn2 = (p + 1 < p1) ? p + 1 : p;
            int en2 = sorted[pn2];
            LOADF(fa, en2);
            kk = en >> 25;
            if (kk != curk) { curk = kk; LOADW(kk); }
            COMPUTE(fb, en);
            ec = en2;
            if (++p >= p1) break;
        }
    }
    __syncthreads();

    // coalesced writeout of the chunk (also covers zero-pair rows)
    const float4* a4 = (const float4*)accS;
    const int n4 = CHUNK_ROWS * RUN_OUTC / 4;                // 1536
    const int base4 = chunk * n4;
    for (int i = threadIdx.x; i < n4; i += 512) {
        int g = base4 + i;
        if (g < NPTS * RUN_OUTC / 4) out4[g] = a4[i];
    }
}

// ---------------------------------------------------------------------------
// Fallback (ws too small): R2 atomic kernel
__global__ __launch_bounds__(256) void conv_gather_scatter(
    const float* __restrict__ features, const float* __restrict__ kernel,
    const int* __restrict__ in_idx, const int* __restrict__ out_idx,
    const int* __restrict__ mask, float* __restrict__ out)
{
    __shared__ float W[RUN_INC][RUN_OUTC];
    const int k = blockIdx.y;
    const int a = k / 9, b = (k / 3) % 3, c = k % 3;
    const int kf = ((a + 1) * KS_FULL + (b + 1)) * KS_FULL + (c + 1);
    const float* __restrict__ Wsrc = kernel + (size_t)kf * (INC * OUTC);
    for (int e = threadIdx.x; e < RUN_INC * RUN_OUTC; e += 256) {
        const int i = e / RUN_OUTC;
        const int o = e - i * RUN_OUTC;
        W[i][o] = Wsrc[i * OUTC + o];
    }
    __syncthreads();
    const int m = blockIdx.x * 256 + threadIdx.x;
    if (m >= MPAIR) return;
    const int pair = k * MPAIR + m;
    if (!mask[pair]) return;
    const int in_row = in_idx[pair], out_row = out_idx[pair];
    const float4* __restrict__ frow = (const float4*)(features + (size_t)in_row * RUN_INC);
    float f[RUN_INC];
    #pragma unroll
    for (int i = 0; i < RUN_INC / 4; ++i) {
        const float4 v = frow[i];
        f[4 * i] = v.x; f[4 * i + 1] = v.y; f[4 * i + 2] = v.z; f[4 * i + 3] = v.w;
    }
    float acc[RUN_OUTC];
    #pragma unroll
    for (int o = 0; o < RUN_OUTC; ++o) acc[o] = 0.0f;
    #pragma unroll 4
    for (int i = 0; i < RUN_INC; ++i) {
        const float fi = f[i];
        const float4* __restrict__ w4 = (const float4*)(&W[i][0]);
        #pragma unroll
        for (int o4 = 0; o4 < RUN_OUTC / 4; ++o4) {
            const float4 w = w4[o4];
            acc[4 * o4 + 0] = fmaf(fi, w.x, acc[4 * o4 + 0]);
            acc[4 * o4 + 1] = fmaf(fi, w.y, acc[4 * o4 + 1]);
            acc[4 * o4 + 2] = fmaf(fi, w.z, acc[4 * o4 + 2]);
            acc[4 * o4 + 3] = fmaf(fi, w.w, acc[4 * o4 + 3]);
        }
    }
    float* __restrict__ orow = out + (size_t)out_row * RUN_OUTC;
    #pragma unroll
    for (int o = 0; o < RUN_OUTC; ++o) unsafeAtomicAdd(orow + o, acc[o]);
}

// ---------------------------------------------------------------------------
extern "C" void kernel_launch(void* const* d_in, const int* in_sizes, int n_in,
                              void* d_out, int out_size, void* d_ws, size_t ws_size,
                              hipStream_t stream) {
    const float* features = (const float*)d_in[0];
    const float* kernel_w = (const float*)d_in[1];
    const int*   in_idx   = (const int*)d_in[2];
    const int*   out_idx  = (const int*)d_in[3];
    const int*   mask     = (const int*)d_in[4];
    float*       out      = (float*)d_out;

    if (ws_size < WS_NEED) {
        hipMemsetAsync(out, 0, (size_t)out_size * sizeof(float), stream);
        dim3 grid((MPAIR + 255) / 256, K_RUN);
        conv_gather_scatter<<<grid, 256, 0, stream>>>(
            features, kernel_w, in_idx, out_idx, mask, out);
        return;
    }

    char* ws = (char*)d_ws;
    int*            counts  = (int*)(ws + OFF_COUNTS);
    int*            offsets = (int*)(ws + OFF_OFFSETS);
    int*            cursor  = (int*)(ws + OFF_CURSOR);
    int*            bsums   = (int*)(ws + OFF_BSUMS);
    unsigned short* wbf     = (unsigned short*)(ws + OFF_WBF);
    uint4*          fbf4    = (uint4*)(ws + OFF_FBF);
    int*            sorted  = (int*)(ws + OFF_SORTED);

    hipMemsetAsync(counts, 0, (size_t)NSCANB * sizeof(int), stream);

    prep_wbf<<<(K_RUN * RUN_INC * RUN_OUTC + 255) / 256, 256, 0, stream>>>(
        kernel_w, wbf);
    prep_fbf<<<((NPTS * RUN_INC / 8) + 255) / 256, 256, 0, stream>>>(
        (const float4*)features, fbf4);

    dim3 pgrid((MPAIR / 4 + 255) / 256, K_RUN);
    hist_kernel<<<pgrid, 256, 0, stream>>>(
        (const int4*)out_idx, (const int4*)mask, counts);

    scan1_kernel<<<NB1, 256, 0, stream>>>(counts, offsets, bsums);
    scan2_kernel<<<1, 256, 0, stream>>>(bsums);
    scan3_kernel<<<(NSCANB + 255) / 256, 256, 0, stream>>>(offsets, bsums, cursor);

    fill_kernel<<<pgrid, 256, 0, stream>>>(
        (const int4*)in_idx, (const int4*)out_idx, (const int4*)mask,
        cursor, sorted);

    accum5_kernel<<<NCHUNK, 512, 0, stream>>>(
        fbf4, (const uint4*)wbf, offsets, sorted, (float4*)out);
}

// Round 9
// 889.790 us; speedup vs baseline: 1.0453x; 1.0453x over previous
//
#include <hip/hip_runtime.h>
#include <hip/hip_bf16.h>

// Problem constants (match reference)
#define KS_FULL 5
#define INC 64
#define OUTC 64
#define RUN_INC 48
#define RUN_OUTC 48
#define NPTS 200000
#define MPAIR 150000
#define K_RUN 27
#define NPAIRS (K_RUN * MPAIR)                 // 4,050,000

// Row-chunk / bucket sort geometry
#define CHUNK_ROWS 128
#define NCHUNK ((NPTS + CHUNK_ROWS - 1) / CHUNK_ROWS)   // 1563
#define NBUCK (NCHUNK * K_RUN)                          // 42,201
#define NSCANB (NBUCK + 1)                              // 42,202
#define SCAN_CHUNK 1024
#define NB1 ((NSCANB + SCAN_CHUNK - 1) / SCAN_CHUNK)    // 42

// d_ws layout (byte offsets). Need ~37.2 MB (R5/R8 confirmed ws is enough).
#define OFF_COUNTS  0u                         // int[NSCANB]
#define OFF_OFFSETS (256u << 10)               // int[NSCANB]
#define OFF_CURSOR  (512u << 10)               // int[NBUCK]
#define OFF_BSUMS   (768u << 10)               // int[NB1]
#define OFF_WBF     (832u << 10)               // ushort[27*6*48*8] = 124,416 B
#define OFF_FBF     (1u << 20)                 // ushort[200000*48] = 19.2 MB
#define OFF_SORTED  (21u << 20)                // int[NPAIRS] = 16.2 MB
#define WS_NEED ((size_t)OFF_SORTED + (size_t)NPAIRS * 4)

// phase0 fused-grid partition
#define NW_BLOCKS 243                          // prep_wbf: 62208/256
#define NF_BLOCKS 4688                         // prep_fbf: 1,200,000/256
#define NH_PERK   147                          // hist: 37500/256 per k
#define NH_BLOCKS (NH_PERK * K_RUN)            // 3969
#define P0_BLOCKS (NW_BLOCKS + NF_BLOCKS + NH_BLOCKS)

// ---------------------------------------------------------------------------
// bf16 helpers
__device__ __forceinline__ unsigned short bf_rne(float x) {
    unsigned u = __float_as_uint(x);
    u += 0x7FFFu + ((u >> 16) & 1u);
    return (unsigned short)(u >> 16);
}
__device__ __forceinline__ unsigned pack2bf(float lo, float hi) {
    return (unsigned)bf_rne(lo) | ((unsigned)bf_rne(hi) << 16);
}

#if defined(__has_builtin)
#if __has_builtin(__builtin_amdgcn_fdot2_f32_bf16)
#define HAVE_DOT2 1
#endif
#endif

#ifdef HAVE_DOT2
typedef __bf16 bf16x2 __attribute__((ext_vector_type(2)));
__device__ __forceinline__ float dot2bf(unsigned w, unsigned f, float c) {
    return __builtin_amdgcn_fdot2_f32_bf16(__builtin_bit_cast(bf16x2, w),
                                           __builtin_bit_cast(bf16x2, f), c, false);
}
#else
__device__ __forceinline__ float dot2bf(unsigned w, unsigned f, float c) {
    c = fmaf(__uint_as_float(w << 16), __uint_as_float(f << 16), c);
    c = fmaf(__uint_as_float(w & 0xFFFF0000u), __uint_as_float(f & 0xFFFF0000u), c);
    return c;
}
#endif

// ---------------------------------------------------------------------------
// phase0: fused prep_wbf + prep_fbf + hist (independent work, one launch)
__global__ __launch_bounds__(256) void phase0_kernel(
    const float* __restrict__ kernel, unsigned short* __restrict__ wbf,
    const float4* __restrict__ f4, uint4* __restrict__ fb4,
    const int4* __restrict__ out_idx4, const int4* __restrict__ mask4,
    int* __restrict__ counts)
{
    const int b = blockIdx.x;
    if (b < NW_BLOCKS) {
        int t = b * 256 + threadIdx.x;
        if (t >= K_RUN * RUN_INC * RUN_OUTC) return;
        int k = t / (RUN_INC * RUN_OUTC);
        int r = t - k * (RUN_INC * RUN_OUTC);
        int i = r / RUN_OUTC;
        int o = r - i * RUN_OUTC;
        int a = k / 9, bb = (k / 3) % 3, c = k % 3;
        int kf = (a + 1) * (KS_FULL * KS_FULL) + (bb + 1) * KS_FULL + (c + 1);
        float v = kernel[(size_t)kf * (INC * OUTC) + i * OUTC + o];
        wbf[(((k * 6 + (i >> 3)) * RUN_OUTC + o) << 3) + (i & 7)] = bf_rne(v);
    } else if (b < NW_BLOCKS + NF_BLOCKS) {
        int t = (b - NW_BLOCKS) * 256 + threadIdx.x;
        if (t >= (NPTS * RUN_INC) / 8) return;
        float4 a = f4[2 * t], bb = f4[2 * t + 1];
        uint4 o;
        o.x = pack2bf(a.x, a.y); o.y = pack2bf(a.z, a.w);
        o.z = pack2bf(bb.x, bb.y); o.w = pack2bf(bb.z, bb.w);
        fb4[t] = o;
    } else {
        int idx = b - NW_BLOCKS - NF_BLOCKS;
        int k = idx / NH_PERK;
        int t = (idx - k * NH_PERK) * 256 + threadIdx.x;
        if (t >= MPAIR / 4) return;
        int base = k * (MPAIR / 4) + t;
        int4 mk = mask4[base];
        int4 oi = out_idx4[base];
        if (mk.x) atomicAdd(&counts[(oi.x >> 7) * K_RUN + k], 1);
        if (mk.y) atomicAdd(&counts[(oi.y >> 7) * K_RUN + k], 1);
        if (mk.z) atomicAdd(&counts[(oi.z >> 7) * K_RUN + k], 1);
        if (mk.w) atomicAdd(&counts[(oi.w >> 7) * K_RUN + k], 1);
    }
}

// ---------------------------------------------------------------------------
// scan1/2/3: exclusive scan of counts[NSCANB] -> offsets (+ cursor copy)
__global__ __launch_bounds__(256) void scan1_kernel(
    const int* __restrict__ counts, int* __restrict__ offsets,
    int* __restrict__ bsums)
{
    __shared__ int sh[2][256];
    int b = blockIdx.x, t = threadIdx.x;
    int gbase = b * SCAN_CHUNK + t * 4;
    int v0 = (gbase + 0 < NSCANB) ? counts[gbase + 0] : 0;
    int v1 = (gbase + 1 < NSCANB) ? counts[gbase + 1] : 0;
    int v2 = (gbase + 2 < NSCANB) ? counts[gbase + 2] : 0;
    int v3 = (gbase + 3 < NSCANB) ? counts[gbase + 3] : 0;
    int tsum = v0 + v1 + v2 + v3;
    sh[0][t] = tsum;
    __syncthreads();
    int src = 0;
    for (int d = 1; d < 256; d <<= 1) {
        int dst = src ^ 1;
        sh[dst][t] = sh[src][t] + ((t >= d) ? sh[src][t - d] : 0);
        __syncthreads();
        src = dst;
    }
    int incl = sh[src][t];
    int excl = incl - tsum;
    if (t == 255) bsums[b] = incl;
    int run = excl;
    if (gbase + 0 < NSCANB) { offsets[gbase + 0] = run; } run += v0;
    if (gbase + 1 < NSCANB) { offsets[gbase + 1] = run; } run += v1;
    if (gbase + 2 < NSCANB) { offsets[gbase + 2] = run; } run += v2;
    if (gbase + 3 < NSCANB) { offsets[gbase + 3] = run; }
}

__global__ __launch_bounds__(256) void scan2_kernel(int* __restrict__ bsums)
{
    __shared__ int sh[2][256];
    int t = threadIdx.x;
    int v = (t < NB1) ? bsums[t] : 0;
    sh[0][t] = v;
    __syncthreads();
    int src = 0;
    for (int d = 1; d < 256; d <<= 1) {
        int dst = src ^ 1;
        sh[dst][t] = sh[src][t] + ((t >= d) ? sh[src][t - d] : 0);
        __syncthreads();
        src = dst;
    }
    if (t < NB1) bsums[t] = sh[src][t] - v;  // exclusive
}

__global__ __launch_bounds__(256) void scan3_kernel(
    int* __restrict__ offsets, const int* __restrict__ bsums,
    int* __restrict__ cursor)
{
    int gi = blockIdx.x * 256 + threadIdx.x;
    if (gi < NSCANB) {
        int v = offsets[gi] + bsums[gi >> 10];
        offsets[gi] = v;
        if (gi < NBUCK) cursor[gi] = v;
    }
}

// ---------------------------------------------------------------------------
// fill: scatter packed (in_row | row_lo<<18 | k<<25) into bucket-sorted slots
__global__ __launch_bounds__(256) void fill_kernel(
    const int4* __restrict__ in_idx4, const int4* __restrict__ out_idx4,
    const int4* __restrict__ mask4, int* __restrict__ cursor,
    int* __restrict__ sorted)
{
    int t = blockIdx.x * 256 + threadIdx.x;
    if (t >= MPAIR / 4) return;
    int k = blockIdx.y;
    int base = k * (MPAIR / 4) + t;
    int4 mk = mask4[base];
    int4 oi = out_idx4[base];
    int4 ii = in_idx4[base];
    int kk = k << 25;
    if (mk.x) { int pos = atomicAdd(&cursor[(oi.x >> 7) * K_RUN + k], 1);
                sorted[pos] = ii.x | ((oi.x & 127) << 18) | kk; }
    if (mk.y) { int pos = atomicAdd(&cursor[(oi.y >> 7) * K_RUN + k], 1);
                sorted[pos] = ii.y | ((oi.y & 127) << 18) | kk; }
    if (mk.z) { int pos = atomicAdd(&cursor[(oi.z >> 7) * K_RUN + k], 1);
                sorted[pos] = ii.z | ((oi.z & 127) << 18) | kk; }
    if (mk.w) { int pos = atomicAdd(&cursor[(oi.w >> 7) * K_RUN + k], 1);
                sorted[pos] = ii.w | ((oi.w & 127) << 18) | kk; }
}

// ---------------------------------------------------------------------------
// accum v5: chunk/k-sorted as R8, but DEPTH-3 software pipeline with
// sched_barrier(0) fences so hipcc cannot sink the prefetch loads (R8: it
// coalesced fa/fb -> VGPR 44, pipeline deleted, full gather latency exposed).
// Static buffer rotation fa->fb->fc (rule #20: no dynamic indexing).
#define LOADF(Fr, e) do { const uint4* fp_ = fbf4 + (size_t)((e) & 0x3FFFF) * 6; \
    Fr##0 = fp_[0]; Fr##1 = fp_[1]; Fr##2 = fp_[2];                              \
    Fr##3 = fp_[3]; Fr##4 = fp_[4]; Fr##5 = fp_[5]; } while (0)

#define LOADW(kk) do { const uint4* wp_ = wbf4 + (size_t)(kk) * (6 * RUN_OUTC) + wo; \
    w0 = wp_[0]; w1 = wp_[RUN_OUTC]; w2 = wp_[2 * RUN_OUTC];                         \
    w3 = wp_[3 * RUN_OUTC]; w4 = wp_[4 * RUN_OUTC]; w5 = wp_[5 * RUN_OUTC]; } while (0)

#define DOTIC(Wv, Fv)                                         \
    a0 = dot2bf(Wv.x, Fv.x, a0); a1 = dot2bf(Wv.y, Fv.y, a1); \
    a2 = dot2bf(Wv.z, Fv.z, a2); a3 = dot2bf(Wv.w, Fv.w, a3);

#define COMPUTE(Fr, e) do {                                   \
    float a0 = 0.f, a1 = 0.f, a2 = 0.f, a3 = 0.f;             \
    DOTIC(w0, Fr##0) DOTIC(w1, Fr##1) DOTIC(w2, Fr##2)        \
    DOTIC(w3, Fr##3) DOTIC(w4, Fr##4) DOTIC(w5, Fr##5)        \
    float s_ = (a0 + a1) + (a2 + a3);                         \
    int rl_ = ((e) >> 18) & (CHUNK_ROWS - 1);                 \
    if (lane < RUN_OUTC)                                      \
        atomicAdd(&accS[rl_ * RUN_OUTC + lane], s_);          \
} while (0)

// one pipeline body: fetch entry p+3, swap W if k changed, compute current
// pair (buffer Fr, entry Er), then refill Fr with pair p+3's features.
#define PIPE_BODY(Fr, Er) do {                                \
    int pn_ = p + 3;                                          \
    int en_ = sorted[pn_ < p1 ? pn_ : (p1 - 1)];              \
    int kk_ = (Er) >> 25;                                     \
    if (kk_ != curk) { curk = kk_; LOADW(kk_); }              \
    __builtin_amdgcn_sched_barrier(0);                        \
    COMPUTE(Fr, Er);                                          \
    __builtin_amdgcn_sched_barrier(0);                        \
    LOADF(Fr, en_); Er = en_;                                 \
    ++p; --n;                                                 \
} while (0)

__global__ __launch_bounds__(512, 4) void accum6_kernel(
    const uint4* __restrict__ fbf4,     // bf16 features, 6 uint4 per row
    const uint4* __restrict__ wbf4,     // 27*6*48 uint4, k-major
    const int* __restrict__ offsets,    // bucket offsets (NSCANB)
    const int* __restrict__ sorted,
    float4* __restrict__ out4)
{
    __shared__ float accS[CHUNK_ROWS * RUN_OUTC];   // 24,576 B
    const int chunk = blockIdx.x;
    for (int i = threadIdx.x; i < CHUNK_ROWS * RUN_OUTC; i += 512) accS[i] = 0.f;
    __syncthreads();

    const int lane = threadIdx.x & 63;
    const int wv   = threadIdx.x >> 6;                       // 0..7
    const int wo   = (lane < RUN_OUTC) ? lane : lane - RUN_OUTC;
    const int S = offsets[chunk * K_RUN];
    const int E = offsets[(chunk + 1) * K_RUN];
    const int P = E - S;
    int p        = S + (int)(((long long)P * wv) >> 3);
    const int p1 = S + (int)(((long long)P * (wv + 1)) >> 3);

    if (p < p1) {
        uint4 w0, w1, w2, w3, w4, w5;
        uint4 fa0, fa1, fa2, fa3, fa4, fa5;
        uint4 fb0, fb1, fb2, fb3, fb4, fb5;
        uint4 fc0, fc1, fc2, fc3, fc4, fc5;
        int curk = -1;
        int n = p1 - p;

        int ea = sorted[p];
        int eb = (p + 1 < p1) ? sorted[p + 1] : ea;
        int ec = (p + 2 < p1) ? sorted[p + 2] : eb;
        LOADF(fa, ea); LOADF(fb, eb); LOADF(fc, ec);

        for (;;) {
            PIPE_BODY(fa, ea); if (n == 0) break;
            PIPE_BODY(fb, eb); if (n == 0) break;
            PIPE_BODY(fc, ec); if (n == 0) break;
        }
    }
    __syncthreads();

    // coalesced writeout of the chunk (also covers zero-pair rows)
    const float4* a4 = (const float4*)accS;
    const int n4 = CHUNK_ROWS * RUN_OUTC / 4;                // 1536
    const int base4 = chunk * n4;
    for (int i = threadIdx.x; i < n4; i += 512) {
        int g = base4 + i;
        if (g < NPTS * RUN_OUTC / 4) out4[g] = a4[i];
    }
}

// ---------------------------------------------------------------------------
// Fallback (ws too small): R2 atomic kernel
__global__ __launch_bounds__(256) void conv_gather_scatter(
    const float* __restrict__ features, const float* __restrict__ kernel,
    const int* __restrict__ in_idx, const int* __restrict__ out_idx,
    const int* __restrict__ mask, float* __restrict__ out)
{
    __shared__ float W[RUN_INC][RUN_OUTC];
    const int k = blockIdx.y;
    const int a = k / 9, b = (k / 3) % 3, c = k % 3;
    const int kf = ((a + 1) * KS_FULL + (b + 1)) * KS_FULL + (c + 1);
    const float* __restrict__ Wsrc = kernel + (size_t)kf * (INC * OUTC);
    for (int e = threadIdx.x; e < RUN_INC * RUN_OUTC; e += 256) {
        const int i = e / RUN_OUTC;
        const int o = e - i * RUN_OUTC;
        W[i][o] = Wsrc[i * OUTC + o];
    }
    __syncthreads();
    const int m = blockIdx.x * 256 + threadIdx.x;
    if (m >= MPAIR) return;
    const int pair = k * MPAIR + m;
    if (!mask[pair]) return;
    const int in_row = in_idx[pair], out_row = out_idx[pair];
    const float4* __restrict__ frow = (const float4*)(features + (size_t)in_row * RUN_INC);
    float f[RUN_INC];
    #pragma unroll
    for (int i = 0; i < RUN_INC / 4; ++i) {
        const float4 v = frow[i];
        f[4 * i] = v.x; f[4 * i + 1] = v.y; f[4 * i + 2] = v.z; f[4 * i + 3] = v.w;
    }
    float acc[RUN_OUTC];
    #pragma unroll
    for (int o = 0; o < RUN_OUTC; ++o) acc[o] = 0.0f;
    #pragma unroll 4
    for (int i = 0; i < RUN_INC; ++i) {
        const float fi = f[i];
        const float4* __restrict__ w4 = (const float4*)(&W[i][0]);
        #pragma unroll
        for (int o4 = 0; o4 < RUN_OUTC / 4; ++o4) {
            const float4 w = w4[o4];
            acc[4 * o4 + 0] = fmaf(fi, w.x, acc[4 * o4 + 0]);
            acc[4 * o4 + 1] = fmaf(fi, w.y, acc[4 * o4 + 1]);
            acc[4 * o4 + 2] = fmaf(fi, w.z, acc[4 * o4 + 2]);
            acc[4 * o4 + 3] = fmaf(fi, w.w, acc[4 * o4 + 3]);
        }
    }
    float* __restrict__ orow = out + (size_t)out_row * RUN_OUTC;
    #pragma unroll
    for (int o = 0; o < RUN_OUTC; ++o) unsafeAtomicAdd(orow + o, acc[o]);
}

// ---------------------------------------------------------------------------
extern "C" void kernel_launch(void* const* d_in, const int* in_sizes, int n_in,
                              void* d_out, int out_size, void* d_ws, size_t ws_size,
                              hipStream_t stream) {
    const float* features = (const float*)d_in[0];
    const float* kernel_w = (const float*)d_in[1];
    const int*   in_idx   = (const int*)d_in[2];
    const int*   out_idx  = (const int*)d_in[3];
    const int*   mask     = (const int*)d_in[4];
    float*       out      = (float*)d_out;

    if (ws_size < WS_NEED) {
        hipMemsetAsync(out, 0, (size_t)out_size * sizeof(float), stream);
        dim3 grid((MPAIR + 255) / 256, K_RUN);
        conv_gather_scatter<<<grid, 256, 0, stream>>>(
            features, kernel_w, in_idx, out_idx, mask, out);
        return;
    }

    char* ws = (char*)d_ws;
    int*            counts  = (int*)(ws + OFF_COUNTS);
    int*            offsets = (int*)(ws + OFF_OFFSETS);
    int*            cursor  = (int*)(ws + OFF_CURSOR);
    int*            bsums   = (int*)(ws + OFF_BSUMS);
    unsigned short* wbf     = (unsigned short*)(ws + OFF_WBF);
    uint4*          fbf4    = (uint4*)(ws + OFF_FBF);
    int*            sorted  = (int*)(ws + OFF_SORTED);

    hipMemsetAsync(counts, 0, (size_t)NSCANB * sizeof(int), stream);

    phase0_kernel<<<P0_BLOCKS, 256, 0, stream>>>(
        kernel_w, wbf, (const float4*)features, fbf4,
        (const int4*)out_idx, (const int4*)mask, counts);

    scan1_kernel<<<NB1, 256, 0, stream>>>(counts, offsets, bsums);
    scan2_kernel<<<1, 256, 0, stream>>>(bsums);
    scan3_kernel<<<(NSCANB + 255) / 256, 256, 0, stream>>>(offsets, bsums, cursor);

    dim3 pgrid((MPAIR / 4 + 255) / 256, K_RUN);
    fill_kernel<<<pgrid, 256, 0, stream>>>(
        (const int4*)in_idx, (const int4*)out_idx, (const int4*)mask,
        cursor, sorted);

    accum6_kernel<<<NCHUNK, 512, 0, stream>>>(
        fbf4, (const uint4*)wbf, offsets, sorted, (float4*)out);
}